// Round 1
// baseline (932.023 us; speedup 1.0000x reference)
//
#include <hip/hip_runtime.h>
#include <cstddef>

#define C_X   48      // channels in x: 3*12 env + 4*3 noise params
#define NB    8       // batch
#define NT    2048    // time
#define TT    64      // t-chunk for lats kernel

// ---------------------------------------------------------------------------
// Kernel 1: per-(b,c) mean over time of x  ->  means[b*48+c]
// ---------------------------------------------------------------------------
__global__ __launch_bounds__(64) void means_kernel(const float* __restrict__ x,
                                                   float* __restrict__ means,
                                                   int T) {
    int bc = blockIdx.x;                 // b*48 + c
    int b = bc / C_X, c = bc % C_X;
    float s = 0.f;
    for (int t = threadIdx.x; t < T; t += 64)
        s += x[((size_t)b * T + t) * C_X + c];
    #pragma unroll
    for (int off = 32; off > 0; off >>= 1)
        s += __shfl_down(s, off);
    if (threadIdx.x == 0) means[bc] = s / (float)T;
}

// ---------------------------------------------------------------------------
// Kernel 2: lats (mean-centered einsum), one pass.
// grid = (B, 18, T/TT), block = 128 threads (each owns one float4 of L=512).
// Each thread holds its 12 table float4s in registers, reused over TT t's.
// ---------------------------------------------------------------------------
__global__ __launch_bounds__(128) void lats_kernel(const float* __restrict__ x,
                                                   const float* __restrict__ table,
                                                   const float* __restrict__ means,
                                                   float* __restrict__ out,
                                                   int T) {
    const int b  = blockIdx.x;
    const int w  = blockIdx.y;           // 0..17
    const int tc = blockIdx.z;           // t-chunk
    const int i  = w / 6;                // part
    const int wl = w % 6;
    const int tid = threadIdx.x;         // 0..127
    const int l  = tid * 4;

    // table slice for this w, in registers: 12 x float4 = 48 VGPRs
    float4 tab[12];
    #pragma unroll
    for (int h = 0; h < 12; ++h)
        tab[h] = *(const float4*)&table[(((size_t)(i * 12 + h) * 18) + (i * 6 + wl)) * 512 + l];

    // centered env values for TT timesteps, staged in LDS (768 floats)
    __shared__ float env_s[TT][12];
    for (int idx = tid; idx < TT * 12; idx += 128) {
        int tt = idx / 12, h = idx % 12;
        int t  = tc * TT + tt;
        env_s[tt][h] = x[((size_t)(b * T + t)) * C_X + i * 12 + h]
                     - means[b * C_X + i * 12 + h];
    }
    __syncthreads();

    size_t obase = (((size_t)(b * T + tc * TT)) * 18 + w) * 512 + l;
    const size_t ostride = (size_t)18 * 512;
    for (int tt = 0; tt < TT; ++tt) {
        float4 acc = make_float4(0.f, 0.f, 0.f, 0.f);
        #pragma unroll
        for (int h = 0; h < 12; ++h) {
            float e = env_s[tt][h];
            acc.x += e * tab[h].x;
            acc.y += e * tab[h].y;
            acc.z += e * tab[h].z;
            acc.w += e * tab[h].w;
        }
        *(float4*)&out[obase + (size_t)tt * ostride] = acc;
    }
}

// ---------------------------------------------------------------------------
// Kernel 3: fused noise build + variable-sigma 9-tap Gaussian along T,
// reflect boundary. Sliding register window: each eps element read once
// (+ 8-element halo per t-chunk). block = 256 threads.
// thread -> (p = p_tile*PP + tid%PP, lane = tid/PP owns TC consecutive t's)
// ---------------------------------------------------------------------------
__global__ __launch_bounds__(256) void noise_kernel(const float* __restrict__ x,
                                                    const float* __restrict__ eps,
                                                    const float* __restrict__ means,
                                                    float* __restrict__ out,
                                                    int T, int P, int PP, int TC,
                                                    int ch_base) {
    const int tid   = threadIdx.x;
    const int pp    = tid % PP;
    const int lane  = tid / PP;
    const int lanes = blockDim.x / PP;
    const int b     = blockIdx.x;
    const int p     = blockIdx.y * PP + pp;
    const int t0    = (blockIdx.z * lanes + lane) * TC;

    // per-batch Gaussian weights (recomputed per thread; 9 expf, cheap)
    float sigma = fmaxf(means[b * C_X + ch_base + 2], 0.001f);
    float inv2s2 = -0.5f / (sigma * sigma);
    float w[9];
    float wsum = 0.f;
    #pragma unroll
    for (int j = 0; j < 9; ++j) {
        float k = (float)(j - 4);
        w[j] = expf(k * k * inv2s2);
        wsum += w[j];
    }
    float winv = 1.0f / wsum;
    #pragma unroll
    for (int j = 0; j < 9; ++j) w[j] *= winv;

    auto raw = [&](int tt) -> float {
        if (tt < 0)  tt = -tt;                 // reflect (edge excluded)
        if (tt >= T) tt = 2 * T - 2 - tt;
        size_t row = (size_t)(b * T + tt);
        float mu = x[row * C_X + ch_base];
        float sg = x[row * C_X + ch_base + 1];
        return mu + sg * eps[row * (size_t)P + p];
    };

    float win[9];
    #pragma unroll
    for (int j = 0; j < 8; ++j) win[j + 1] = raw(t0 - 4 + j);

    for (int t = t0; t < t0 + TC; ++t) {
        #pragma unroll
        for (int j = 0; j < 8; ++j) win[j] = win[j + 1];
        win[8] = raw(t + 4);
        float acc = 0.f;
        #pragma unroll
        for (int j = 0; j < 9; ++j) acc += w[j] * win[j];
        out[(size_t)(b * T + t) * P + p] = acc;
    }
}

// ---------------------------------------------------------------------------
extern "C" void kernel_launch(void* const* d_in, const int* in_sizes, int n_in,
                              void* d_out, int out_size, void* d_ws, size_t ws_size,
                              hipStream_t stream) {
    const float* x     = (const float*)d_in[0];
    const float* table = (const float*)d_in[1];
    const float* epss[4] = {(const float*)d_in[2], (const float*)d_in[3],
                            (const float*)d_in[4], (const float*)d_in[5]};
    float* out   = (float*)d_out;
    float* means = (float*)d_ws;     // 8*48 floats

    const int B = NB, T = NT;

    // 1) time-means of all 48 channels
    means_kernel<<<B * C_X, 64, 0, stream>>>(x, means, T);

    // 2) centered lats, one pass
    dim3 gl(B, 18, T / TT);
    lats_kernel<<<gl, 128, 0, stream>>>(x, table, means, out, T);

    // 3) four noise streams
    size_t off = (size_t)B * T * 18 * 512;
    const int Ps[4]  = {16, 64, 256, 1024};
    const int PPs[4] = {16, 64, 256, 256};
    const int TCs[4] = {32, 32, 64, 64};
    for (int i = 0; i < 4; ++i) {
        int P = Ps[i], PP = PPs[i], TC = TCs[i];
        int lanes = 256 / PP;
        dim3 gn(B, P / PP, T / (lanes * TC));
        noise_kernel<<<gn, 256, 0, stream>>>(x, epss[i], means, out + off,
                                             T, P, PP, TC, 36 + 3 * i);
        off += (size_t)B * T * P;
    }
}